// Round 4
// baseline (412.913 us; speedup 1.0000x reference)
//
#include <hip/hip_runtime.h>
#include <hip/hip_bf16.h>
#include <math.h>

#define N_SAMP 32768
#define NPAIR  (N_SAMP/2)
#define NBLK   768                 // real run: exactly 3 blocks/CU
#define NBLK2  96                  // profiling probe: long dispatch -> visible counters
#define PROBE_OFF (16*1024*1024)   // float offset into ws for probe output

typedef short bf16x8 __attribute__((ext_vector_type(8)));
typedef float f32x4  __attribute__((ext_vector_type(4)));

__device__ __forceinline__ float dot4(const float4& a, const float4& b) {
    return a.x*b.x + a.y*b.y + a.z*b.z + a.w*b.w;
}
__device__ __forceinline__ ushort f2bfu(float x) {
    __hip_bfloat16 h = __float2bfloat16(x);
    ushort u; __builtin_memcpy(&u, &h, 2); return u;
}
__device__ __forceinline__ unsigned int pk2bf(float x, float y) {
    return (unsigned int)f2bfu(x) | ((unsigned int)f2bfu(y) << 16);
}
__device__ __forceinline__ void gfadd(float* p, float v) {
    __hip_atomic_fetch_add(p, v, __ATOMIC_RELAXED, __HIP_MEMORY_SCOPE_AGENT);
}

// ---------------- main kernel ----------------
// 256 threads = 4 waves; wave owns one PAIR (16 rows x 256 cols) per iter.
// A-fragments loaded DIRECTLY from global in MFMA layout (no LDS staging):
// lane l -> row C=l&15, cols G*8 + kb*32 + j  (G=l>>4, j=0..7).
// Gram = mfma(u,u) -> inv from diag; E = mfma(u, ccn_frag from LDS).
// colsum kept in fragment layout (64 VGPRs), reduced in epilogue.

template<bool ATOMIC>
__global__ __launch_bounds__(256, 3) void nssd_main(const float* __restrict__ gf,
                                                    const float* __restrict__ cc,
                                                    float* __restrict__ ws,
                                                    int nblk)
{
    __shared__ unsigned int lds_stage[4][2048];  // 32 KB: ccn f32 tmp / epilogue colsum
    __shared__ unsigned int lds_ccn[1024];       // 4 KB: ccn bf16 [8][256] XOR-swizzled
    __shared__ float lds_inv[4][16];
    __shared__ float lds_red[8];

    const int tid  = threadIdx.x;
    const int lane = tid & 63;
    const int w    = tid >> 6;

    // ---- normalize cluster_center (f32 tmp in lds_stage) ----
    {
        float* cptr = (float*)lds_stage;
        const int l32 = tid & 31, st = tid >> 5;
        const float4* cc4 = (const float4*)cc;
        float4 a = cc4[st*64 + l32];
        float4 b = cc4[st*64 + 32 + l32];
        float ss = dot4(a,a) + dot4(b,b);
        #pragma unroll
        for (int m = 1; m < 32; m <<= 1) ss += __shfl_xor(ss, m);
        float inv = 1.0f / (sqrtf(ss) + 1e-12f);
        *(float4*)(cptr + st*256 + l32*4)       = make_float4(a.x*inv,a.y*inv,a.z*inv,a.w*inv);
        *(float4*)(cptr + st*256 + 128 + l32*4) = make_float4(b.x*inv,b.y*inv,b.z*inv,b.w*inv);
    }
    __syncthreads();
    // ---- ccn -> bf16 LDS, swizzled: byte = row*512 + ((col*2) ^ (row<<4)) ----
    {
        const float* cptr = (const float*)lds_stage;
        int row = tid >> 5, c0 = (tid & 31) * 8;
        uint4 uu;
        uu.x = pk2bf(cptr[row*256+c0+0], cptr[row*256+c0+1]);
        uu.y = pk2bf(cptr[row*256+c0+2], cptr[row*256+c0+3]);
        uu.z = pk2bf(cptr[row*256+c0+4], cptr[row*256+c0+5]);
        uu.w = pk2bf(cptr[row*256+c0+6], cptr[row*256+c0+7]);
        *(uint4*)((char*)lds_ccn + row*512 + ((c0*2) ^ (row << 4))) = uu;
    }
    __syncthreads();

    char* cbase = (char*)lds_ccn;
    const int G = lane >> 4, C = lane & 15;

    f32x4 colacc[16];                     // [2*kb + half] -> cols kb*32 + G*8 + j
    #pragma unroll
    for (int i = 0; i < 16; ++i) colacc[i] = (f32x4){0.f,0.f,0.f,0.f};
    float l1 = 0.f, l2 = 0.f;

    for (int p = blockIdx.x*4 + w; p < NPAIR; p += nblk*4) {
        // ---- direct fragment loads: 2x dwordx4 per kb, imm-folded offsets ----
        const float* rowp = gf + (size_t)p*4096 + C*256 + G*8;
        bf16x8 u[8];
        #pragma unroll
        for (int kb = 0; kb < 8; ++kb) {
            float4 a = *(const float4*)(rowp + kb*32);
            float4 b = *(const float4*)(rowp + kb*32 + 4);
            uint4 q;
            q.x = pk2bf(a.x,a.y); q.y = pk2bf(a.z,a.w);
            q.z = pk2bf(b.x,b.y); q.w = pk2bf(b.z,b.w);
            __builtin_memcpy(&u[kb], &q, 16);
        }

        // ---- MFMA: Gram (u,u) and E (u,ccn), K=256 in 8 steps ----
        f32x4 accg = (f32x4){0.f,0.f,0.f,0.f};
        f32x4 acce = (f32x4){0.f,0.f,0.f,0.f};
        #pragma unroll
        for (int kb = 0; kb < 8; ++kb) {
            int off = kb*64 + G*16;
            bf16x8 cfrag = *(bf16x8*)(cbase + (C&7)*512 + (off ^ ((C&7)<<4)));
            accg = __builtin_amdgcn_mfma_f32_16x16x32_bf16(u[kb], u[kb],  accg, 0, 0, 0);
            acce = __builtin_amdgcn_mfma_f32_16x16x32_bf16(u[kb], cfrag, acce, 0, 0, 0);
        }

        // ---- inv from Gram diag; broadcast via per-wave LDS ----
        float xd = (lane&3)==0 ? accg[0] : (lane&3)==1 ? accg[1]
                 : (lane&3)==2 ? accg[2] : accg[3];
        float invv = 1.0f / (sqrtf(xd) + 1e-12f);
        if (G == (C >> 2)) lds_inv[w][C] = invv;     // diag lane for row r=C
        f32x4 invrow = *(f32x4*)&lds_inv[w][G*4];
        float invcol = lds_inv[w][C];

        // ---- losses (C/D layout: col=C, row=G*4+reg) ----
        #pragma unroll
        for (int reg = 0; reg < 4; ++reg) {
            int r = G*4 + reg;
            float Cv = accg[reg] * invrow[reg] * invcol;
            bool inblk = ((r >> 3) == (C >> 3));
            float tgt = (r == C) ? 1.0f : 0.0f;
            l1 += inblk ? fabsf(Cv - tgt) : 0.0f;

            float e  = acce[reg] * invrow[reg];
            float Dv = fmaxf(fmaf(-0.5f, e, 0.5f), 1e-12f);
            bool ond = ((C & 7) == (r & 7));
            float dmin = Dv + (ond ? 1.0f : 0.0f);
            float ddia = ond ? Dv : 3e38f;
            #pragma unroll
            for (int m = 1; m < 16; m <<= 1) {
                dmin = fminf(dmin, __shfl_xor(dmin, m));
                ddia = fminf(ddia, __shfl_xor(ddia, m));
            }
            float sp = __logf(1.0f + __expf(ddia - dmin));
            l2 += (C == (r & 7)) ? sp : 0.0f;
        }

        // ---- colsum in fragment layout: lane's row C, scale by invcol ----
        #pragma unroll
        for (int kb = 0; kb < 8; ++kb) {
            uint4 q; __builtin_memcpy(&q, &u[kb], 16);
            colacc[2*kb][0]   += __uint_as_float(q.x << 16)          * invcol;
            colacc[2*kb][1]   += __uint_as_float(q.x & 0xffff0000u)  * invcol;
            colacc[2*kb][2]   += __uint_as_float(q.y << 16)          * invcol;
            colacc[2*kb][3]   += __uint_as_float(q.y & 0xffff0000u)  * invcol;
            colacc[2*kb+1][0] += __uint_as_float(q.z << 16)          * invcol;
            colacc[2*kb+1][1] += __uint_as_float(q.z & 0xffff0000u)  * invcol;
            colacc[2*kb+1][2] += __uint_as_float(q.w << 16)          * invcol;
            colacc[2*kb+1][3] += __uint_as_float(q.w & 0xffff0000u)  * invcol;
        }
    }

    // ---------------- epilogue ----------------
    // combine rows C and C+8 (same stripe, two samples)
    #pragma unroll
    for (int i = 0; i < 16; ++i) {
        #pragma unroll
        for (int j = 0; j < 4; ++j)
            colacc[i][j] += __shfl_xor(colacc[i][j], 8);
    }

    #pragma unroll
    for (int m = 1; m < 64; m <<= 1) { l1 += __shfl_xor(l1, m); l2 += __shfl_xor(l2, m); }
    if (lane == 0) { lds_red[w] = l1; lds_red[4 + w] = l2; }

    // scatter per-wave colsum to LDS [stripe][col]
    if ((lane & 8) == 0) {
        int s = lane & 7;
        char* cf = (char*)&lds_stage[w][0];
        #pragma unroll
        for (int kb = 0; kb < 8; ++kb) {
            *(f32x4*)(cf + s*1024 + kb*128 + G*32)      = colacc[2*kb];
            *(f32x4*)(cf + s*1024 + kb*128 + G*32 + 16) = colacc[2*kb+1];
        }
    }
    __syncthreads();

    const float* lf = (const float*)lds_stage;
    if (ATOMIC) {
        #pragma unroll
        for (int c8 = 0; c8 < 8; ++c8) {
            int idx = c8*256 + tid;
            gfadd(&ws[idx], lf[idx] + lf[2048+idx] + lf[4096+idx] + lf[6144+idx]);
        }
        if (tid == 0) {
            gfadd(&ws[2048], lds_red[0]+lds_red[1]+lds_red[2]+lds_red[3]);
            gfadd(&ws[2049], lds_red[4]+lds_red[5]+lds_red[6]+lds_red[7]);
        }
    } else {
        float* wb = ws + (size_t)blockIdx.x * 2048;
        #pragma unroll
        for (int c8 = 0; c8 < 8; ++c8) {
            int idx = c8*256 + tid;
            wb[idx] = lf[idx] + lf[2048+idx] + lf[4096+idx] + lf[6144+idx];
        }
        if (tid == 0) {
            ws[(size_t)nblk*2048 + blockIdx.x]        = lds_red[0]+lds_red[1]+lds_red[2]+lds_red[3];
            ws[(size_t)nblk*2048 + nblk + blockIdx.x] = lds_red[4]+lds_red[5]+lds_red[6]+lds_red[7];
        }
    }
}

// ---------------- finalize ----------------
// blocks 0..127: new_cc, 16 cols x 16 parallel k-chunks; block 128: loss.

template<int NB>
__global__ __launch_bounds__(256) void nssd_finalize(const float* __restrict__ ws,
                                                     const float* __restrict__ cc,
                                                     float* __restrict__ out,
                                                     int loff)
{
    __shared__ float red[256];
    const int t = threadIdx.x;
    if (blockIdx.x < 128) {
        const int col = blockIdx.x*16 + (t & 15);
        const int kc  = t >> 4;                 // 0..15
        const int chunk = (NB + 15) / 16;
        const int k0 = kc * chunk;
        const int k1 = (k0 + chunk < NB) ? (k0 + chunk) : NB;
        float s0 = 0.f, s1 = 0.f, s2 = 0.f, s3 = 0.f;
        int k = k0;
        for (; k + 4 <= k1; k += 4) {
            s0 += ws[(size_t)(k+0)*2048 + col];
            s1 += ws[(size_t)(k+1)*2048 + col];
            s2 += ws[(size_t)(k+2)*2048 + col];
            s3 += ws[(size_t)(k+3)*2048 + col];
        }
        for (; k < k1; ++k) s0 += ws[(size_t)k*2048 + col];
        red[t] = (s0 + s1) + (s2 + s3);
        __syncthreads();
        if (t < 16) {
            float v = 0.f;
            #pragma unroll
            for (int i = 0; i < 16; ++i) v += red[i*16 + t];
            int o = blockIdx.x*16 + t;
            out[1 + o] = 0.9f*cc[o] + 0.1f*(v * (1.0f/32768.0f));
        }
    } else {
        const float* lp = ws + loff;
        float s1 = 0.f, s2 = 0.f;
        for (int i = t; i < NB; i += 256) { s1 += lp[i]; s2 += lp[NB + i]; }
        #pragma unroll
        for (int m = 1; m <= 32; m <<= 1) { s1 += __shfl_xor(s1, m); s2 += __shfl_xor(s2, m); }
        if ((t & 63) == 0) { red[t >> 6] = s1; red[4 + (t >> 6)] = s2; }
        __syncthreads();
        if (t == 0) {
            float a = red[0] + red[1] + red[2] + red[3];
            float b = red[4] + red[5] + red[6] + red[7];
            out[0] = a * (1.0f/(32768.0f*64.0f)) + b * (1.0f/(32768.0f*8.0f));
        }
    }
}

// ---------------- launch ----------------

extern "C" void kernel_launch(void* const* d_in, const int* in_sizes, int n_in,
                              void* d_out, int out_size, void* d_ws, size_t ws_size,
                              hipStream_t stream)
{
    const float* gf = (const float*)d_in[0];
    const float* cc = (const float*)d_in[1];
    float* out = (float*)d_out;
    float* ws  = (float*)d_ws;

    const size_t need_store = (size_t)(NBLK*2048 + 2*NBLK) * sizeof(float);
    const size_t need_probe = ((size_t)PROBE_OFF + NBLK2*2048 + 2*NBLK2) * sizeof(float);

    if (ws_size >= need_store) {
        hipLaunchKernelGGL((nssd_main<false>), dim3(NBLK), dim3(256), 0, stream,
                           gf, cc, ws, NBLK);
        if (ws_size >= need_probe) {
            // profiling probe: long single dispatch (1 block/CU) to surface
            // FETCH/WRITE/VGPR counters in rocprof top-5. Output unused.
            hipLaunchKernelGGL((nssd_main<false>), dim3(NBLK2), dim3(256), 0, stream,
                               gf, cc, ws + PROBE_OFF, NBLK2);
        }
        hipLaunchKernelGGL((nssd_finalize<NBLK>), dim3(129), dim3(256), 0, stream,
                           ws, cc, out, NBLK*2048);
    } else {
        hipMemsetAsync(ws, 0, 2050*sizeof(float), stream);
        hipLaunchKernelGGL((nssd_main<true>), dim3(NBLK), dim3(256), 0, stream,
                           gf, cc, ws, NBLK);
        hipLaunchKernelGGL((nssd_finalize<1>), dim3(129), dim3(256), 0, stream,
                           ws, cc, out, 2048);
    }
}

// Round 5
// 69.097 us; speedup vs baseline: 5.9759x; 5.9759x over previous
//
#include <hip/hip_runtime.h>
#include <hip/hip_bf16.h>
#include <math.h>

#define N_SAMP 32768
#define NPAIR  (N_SAMP/2)
#define NBLK   768                 // exactly 3 blocks/CU -> 16 iters per CU uniform

typedef short bf16x8 __attribute__((ext_vector_type(8)));
typedef float f32x4  __attribute__((ext_vector_type(4)));

__device__ __forceinline__ float dot4(const float4& a, const float4& b) {
    return a.x*b.x + a.y*b.y + a.z*b.z + a.w*b.w;
}
__device__ __forceinline__ ushort f2bfu(float x) {
    __hip_bfloat16 h = __float2bfloat16(x);
    ushort u; __builtin_memcpy(&u, &h, 2); return u;
}
__device__ __forceinline__ unsigned int pk2bf(float x, float y) {
    return (unsigned int)f2bfu(x) | ((unsigned int)f2bfu(y) << 16);
}
__device__ __forceinline__ void gfadd(float* p, float v) {
    __hip_atomic_fetch_add(p, v, __ATOMIC_RELAXED, __HIP_MEMORY_SCOPE_AGENT);
}

// ---------------- main kernel ----------------
// 256 threads = 4 waves; wave owns one PAIR (16 rows x 256 cols) per iter.
// Coalesced f32 loads -> bf16 -> per-wave XOR-swizzled LDS -> MFMA.
// Gram = mfma(u,u) -> inv from diag via cross-lane (no LDS round-trip);
// E = mfma(u, ccn). colsum from live f32 v[] in row layout (32 VGPRs).
// No block barrier in the main loop.

template<bool ATOMIC>
__global__ __launch_bounds__(256, 3) void nssd_main(const float* __restrict__ gf,
                                                    const float* __restrict__ cc,
                                                    float* __restrict__ ws,
                                                    int nblk)
{
    __shared__ unsigned int lds_stage[4][2048];  // 32 KB: per-wave staging; epilogue colsum
    __shared__ unsigned int lds_ccn[1024];       // 4 KB: ccn bf16 [8][256] XOR-swizzled
    __shared__ float lds_red[8];

    const int tid  = threadIdx.x;
    const int lane = tid & 63;
    const int w    = tid >> 6;

    // ---- normalize cluster_center (f32 tmp in lds_stage) ----
    {
        float* cptr = (float*)lds_stage;
        const int l32 = tid & 31, st = tid >> 5;
        const float4* cc4 = (const float4*)cc;
        float4 a = cc4[st*64 + l32];
        float4 b = cc4[st*64 + 32 + l32];
        float ss = dot4(a,a) + dot4(b,b);
        #pragma unroll
        for (int m = 1; m < 32; m <<= 1) ss += __shfl_xor(ss, m);
        float inv = 1.0f / (sqrtf(ss) + 1e-12f);
        *(float4*)(cptr + st*256 + l32*4)       = make_float4(a.x*inv,a.y*inv,a.z*inv,a.w*inv);
        *(float4*)(cptr + st*256 + 128 + l32*4) = make_float4(b.x*inv,b.y*inv,b.z*inv,b.w*inv);
    }
    __syncthreads();
    // ---- ccn -> bf16 LDS, swizzled: byte = row*512 + ((col*2) ^ (row<<4)) ----
    {
        const float* cptr = (const float*)lds_stage;
        int row = tid >> 5, c0 = (tid & 31) * 8;
        uint4 uu;
        uu.x = pk2bf(cptr[row*256+c0+0], cptr[row*256+c0+1]);
        uu.y = pk2bf(cptr[row*256+c0+2], cptr[row*256+c0+3]);
        uu.z = pk2bf(cptr[row*256+c0+4], cptr[row*256+c0+5]);
        uu.w = pk2bf(cptr[row*256+c0+6], cptr[row*256+c0+7]);
        *(uint4*)((char*)lds_ccn + row*512 + ((c0*2) ^ (row << 4))) = uu;
    }
    __syncthreads();

    char* sbase = (char*)lds_stage + w*8192;
    char* cbase = (char*)lds_ccn;
    const int G = lane >> 4, C = lane & 15;
    const int Ck = (C & 7) << 4;

    f32x4 colacc[8];
    #pragma unroll
    for (int s = 0; s < 8; ++s) colacc[s] = (f32x4){0.f,0.f,0.f,0.f};
    float l1 = 0.f, l2 = 0.f;

    for (int p = blockIdx.x*4 + w; p < NPAIR; p += nblk*4) {
        const float4* g4 = (const float4*)(gf + (size_t)p * 4096);

        // ---- batch-issue 16 coalesced loads (1 KB segments each) ----
        float4 v[16];
        #pragma unroll
        for (int i = 0; i < 16; ++i) v[i] = g4[i*64 + lane];
        __builtin_amdgcn_sched_barrier(0);   // keep all loads issued before any use

        // ---- convert + stage, row by row (u transient, 2 regs at a time) ----
        #pragma unroll
        for (int i = 0; i < 16; ++i) {
            uint2 uu = make_uint2(pk2bf(v[i].x, v[i].y), pk2bf(v[i].z, v[i].w));
            *(uint2*)(sbase + i*512 + ((lane*8) ^ ((i & 7) << 4))) = uu;
        }

        // ---- MFMA: Gram (u,u) and E (u,ccn), K=256 in 8 steps ----
        f32x4 accg = (f32x4){0.f,0.f,0.f,0.f};
        f32x4 acce = (f32x4){0.f,0.f,0.f,0.f};
        #pragma unroll
        for (int kb = 0; kb < 8; ++kb) {
            int off = kb*64 + G*16;
            bf16x8 af = *(bf16x8*)(sbase + C*512     + (off ^ Ck));
            bf16x8 cf = *(bf16x8*)(cbase + (C&7)*512 + (off ^ Ck));
            accg = __builtin_amdgcn_mfma_f32_16x16x32_bf16(af, af, accg, 0, 0, 0);
            acce = __builtin_amdgcn_mfma_f32_16x16x32_bf16(af, cf, acce, 0, 0, 0);
        }

        // ---- inv from Gram diag, distributed via cross-lane only ----
        // diag of row j lives on lane Ld(j) = ((j>>2)<<4)|j as accg[j&3]
        float xd = (lane&3)==0 ? accg[0] : (lane&3)==1 ? accg[1]
                 : (lane&3)==2 ? accg[2] : accg[3];
        float invv = 1.0f / (sqrtf(xd) + 1e-12f);
        float invcol = __shfl(invv, ((C >> 2) << 4) | C);

        // ---- losses (C/D layout: col=C, row=G*4+reg) ----
        #pragma unroll
        for (int reg = 0; reg < 4; ++reg) {
            int r = G*4 + reg;
            float invr = __shfl(invv, (G << 4) | (G*4 + reg));
            float Cv = accg[reg] * invr * invcol;
            bool inblk = ((r >> 3) == (C >> 3));
            float tgt = (r == C) ? 1.0f : 0.0f;
            l1 += inblk ? fabsf(Cv - tgt) : 0.0f;

            float e  = acce[reg] * invr;
            float Dv = fmaxf(fmaf(-0.5f, e, 0.5f), 1e-12f);
            bool ond = ((C & 7) == (r & 7));
            float dmin = Dv + (ond ? 1.0f : 0.0f);
            #pragma unroll
            for (int m = 1; m < 16; m <<= 1)
                dmin = fminf(dmin, __shfl_xor(dmin, m));
            // diag lane's own Dv IS ddiag; count it once (C = r&7 only)
            float sp = __logf(1.0f + __expf(Dv - dmin));
            l2 += (C == (r & 7)) ? sp : 0.0f;
        }

        // ---- colsum from live f32 v[] (row layout): readlane-broadcast invs ----
        #pragma unroll
        for (int s = 0; s < 8; ++s) {
            float ia = __shfl(invv, (( s     >> 2) << 4) |  s     );
            float ib = __shfl(invv, (((s+8)  >> 2) << 4) | (s+8)  );
            colacc[s][0] += v[s].x*ia + v[s+8].x*ib;
            colacc[s][1] += v[s].y*ia + v[s+8].y*ib;
            colacc[s][2] += v[s].z*ia + v[s+8].z*ib;
            colacc[s][3] += v[s].w*ia + v[s+8].w*ib;
        }
    }

    // ---------------- block epilogue ----------------
    #pragma unroll
    for (int m = 1; m < 64; m <<= 1) { l1 += __shfl_xor(l1, m); l2 += __shfl_xor(l2, m); }
    if (lane == 0) { lds_red[w] = l1; lds_red[4 + w] = l2; }

    // per-wave colsum -> own staging region, natural [stripe][256] layout
    float* cf = (float*)&lds_stage[w][0];
    #pragma unroll
    for (int s = 0; s < 8; ++s)
        *(f32x4*)(cf + s*256 + lane*4) = colacc[s];
    __syncthreads();

    const float* lf = (const float*)lds_stage;
    if (ATOMIC) {
        #pragma unroll
        for (int c8 = 0; c8 < 8; ++c8) {
            int idx = c8*256 + tid;
            gfadd(&ws[idx], lf[idx] + lf[2048+idx] + lf[4096+idx] + lf[6144+idx]);
        }
        if (tid == 0) {
            gfadd(&ws[2048], lds_red[0]+lds_red[1]+lds_red[2]+lds_red[3]);
            gfadd(&ws[2049], lds_red[4]+lds_red[5]+lds_red[6]+lds_red[7]);
        }
    } else {
        float* wb = ws + (size_t)blockIdx.x * 2048;
        #pragma unroll
        for (int c8 = 0; c8 < 8; ++c8) {
            int idx = c8*256 + tid;
            wb[idx] = lf[idx] + lf[2048+idx] + lf[4096+idx] + lf[6144+idx];
        }
        if (tid == 0) {
            ws[(size_t)nblk*2048 + blockIdx.x]        = lds_red[0]+lds_red[1]+lds_red[2]+lds_red[3];
            ws[(size_t)nblk*2048 + nblk + blockIdx.x] = lds_red[4]+lds_red[5]+lds_red[6]+lds_red[7];
        }
    }
}

// ---------------- finalize ----------------
// blocks 0..127: new_cc, 16 cols x 16 parallel k-chunks; block 128: loss.

template<int NB>
__global__ __launch_bounds__(256) void nssd_finalize(const float* __restrict__ ws,
                                                     const float* __restrict__ cc,
                                                     float* __restrict__ out,
                                                     int loff)
{
    __shared__ float red[256];
    const int t = threadIdx.x;
    if (blockIdx.x < 128) {
        const int col = blockIdx.x*16 + (t & 15);
        const int kc  = t >> 4;                 // 0..15
        const int chunk = (NB + 15) / 16;
        const int k0 = kc * chunk;
        const int k1 = (k0 + chunk < NB) ? (k0 + chunk) : NB;
        float s0 = 0.f, s1 = 0.f, s2 = 0.f, s3 = 0.f;
        int k = k0;
        for (; k + 4 <= k1; k += 4) {
            s0 += ws[(size_t)(k+0)*2048 + col];
            s1 += ws[(size_t)(k+1)*2048 + col];
            s2 += ws[(size_t)(k+2)*2048 + col];
            s3 += ws[(size_t)(k+3)*2048 + col];
        }
        for (; k < k1; ++k) s0 += ws[(size_t)k*2048 + col];
        red[t] = (s0 + s1) + (s2 + s3);
        __syncthreads();
        if (t < 16) {
            float v = 0.f;
            #pragma unroll
            for (int i = 0; i < 16; ++i) v += red[i*16 + t];
            int o = blockIdx.x*16 + t;
            out[1 + o] = 0.9f*cc[o] + 0.1f*(v * (1.0f/32768.0f));
        }
    } else {
        const float* lp = ws + loff;
        float s1 = 0.f, s2 = 0.f;
        for (int i = t; i < NB; i += 256) { s1 += lp[i]; s2 += lp[NB + i]; }
        #pragma unroll
        for (int m = 1; m <= 32; m <<= 1) { s1 += __shfl_xor(s1, m); s2 += __shfl_xor(s2, m); }
        if ((t & 63) == 0) { red[t >> 6] = s1; red[4 + (t >> 6)] = s2; }
        __syncthreads();
        if (t == 0) {
            float a = red[0] + red[1] + red[2] + red[3];
            float b = red[4] + red[5] + red[6] + red[7];
            out[0] = a * (1.0f/(32768.0f*64.0f)) + b * (1.0f/(32768.0f*8.0f));
        }
    }
}

// ---------------- launch ----------------

extern "C" void kernel_launch(void* const* d_in, const int* in_sizes, int n_in,
                              void* d_out, int out_size, void* d_ws, size_t ws_size,
                              hipStream_t stream)
{
    const float* gf = (const float*)d_in[0];
    const float* cc = (const float*)d_in[1];
    float* out = (float*)d_out;
    float* ws  = (float*)d_ws;

    const size_t need_store = (size_t)(NBLK*2048 + 2*NBLK) * sizeof(float);

    if (ws_size >= need_store) {
        hipLaunchKernelGGL((nssd_main<false>), dim3(NBLK), dim3(256), 0, stream,
                           gf, cc, ws, NBLK);
        hipLaunchKernelGGL((nssd_finalize<NBLK>), dim3(129), dim3(256), 0, stream,
                           ws, cc, out, NBLK*2048);
    } else {
        hipMemsetAsync(ws, 0, 2050*sizeof(float), stream);
        hipLaunchKernelGGL((nssd_main<true>), dim3(NBLK), dim3(256), 0, stream,
                           gf, cc, ws, NBLK);
        hipLaunchKernelGGL((nssd_finalize<1>), dim3(129), dim3(256), 0, stream,
                           ws, cc, out, 2048);
    }
}